// Round 4
// baseline (2167.697 us; speedup 1.0000x reference)
//
#include <hip/hip_runtime.h>
#include <hip/hip_bf16.h>

// ---------------------------------------------------------------------------
// MF_Transformer: B=128, SL=5000, CH=12, HZ=100 -> tokens M=6400, S=50, D=1024
// L=5, DFF=4096, H=16, dk=64, NC=71. All heavy GEMMs in bf16 MFMA (fp32 acc).
// R3: + XCD-chunked bijective block swizzle in gemm_bt (T1/m204) so each XCD
//     owns contiguous row-stripes -> A-panels fetched once per XCD L2.
// (R4 = resubmit of R3; R3 hit a GPU-acquisition timeout, no data.)
// ---------------------------------------------------------------------------

typedef __attribute__((ext_vector_type(4))) float f32x4;
typedef __attribute__((ext_vector_type(8))) __bf16 bfvec8;

#define MTOT 6400      // B*S
#define DMODEL 1024
#define KEMB 1216      // 1200 padded to multiple of 64

__device__ __forceinline__ unsigned short f2bf(float x) {
    __hip_bfloat16 t = __float2bfloat16(x);
    return *reinterpret_cast<unsigned short*>(&t);
}

__device__ __forceinline__ void gl2lds16(const void* g, void* l) {
    __builtin_amdgcn_global_load_lds(
        (__attribute__((address_space(1))) void*)(g),
        (__attribute__((address_space(3))) void*)(l), 16, 0, 0);
}

// ---------------------------------------------------------------------------
// Transpose-convert: W fp32 (K,N) -> Wt bf16 (N,Kpad), zero-pad k in [K,Kpad)
// ---------------------------------------------------------------------------
__global__ __launch_bounds__(256) void tconv(const float* __restrict__ W,
                                             __hip_bfloat16* __restrict__ Wt,
                                             int K, int N, int Kpad) {
    __shared__ float t[32][33];
    const int n0 = blockIdx.x * 32, k0 = blockIdx.y * 32;
    const int tx = threadIdx.x, ty = threadIdx.y;   // block (32,8)
#pragma unroll
    for (int j = 0; j < 4; ++j) {
        int k = k0 + ty + j * 8, n = n0 + tx;
        float v = (k < K && n < N) ? W[(size_t)k * N + n] : 0.f;
        t[ty + j * 8][tx] = v;
    }
    __syncthreads();
#pragma unroll
    for (int j = 0; j < 4; ++j) {
        int n = n0 + ty + j * 8, k = k0 + tx;
        if (n < N && k < Kpad)
            ((unsigned short*)Wt)[(size_t)n * Kpad + k] = f2bf(t[tx][ty + j * 8]);
    }
}

// ---------------------------------------------------------------------------
// x fp32 (6400,1200) -> bf16 (6400,1216) zero-padded
// ---------------------------------------------------------------------------
__global__ __launch_bounds__(256) void xconv(const float* __restrict__ x,
                                             __hip_bfloat16* __restrict__ xb) {
    int q = blockIdx.x * 256 + threadIdx.x;           // quads: 6400*304
    if (q >= MTOT * (KEMB / 4)) return;
    int m = q / (KEMB / 4), kq = q - m * (KEMB / 4);
    ushort4 o;
    if (kq < 300) {
        float4 v = reinterpret_cast<const float4*>(x + (size_t)m * 1200)[kq];
        o.x = f2bf(v.x); o.y = f2bf(v.y); o.z = f2bf(v.z); o.w = f2bf(v.w);
    } else { o.x = 0; o.y = 0; o.z = 0; o.w = 0; }
    reinterpret_cast<ushort4*>(xb)[q] = o;
}

// ---------------------------------------------------------------------------
// positional encoding table (50,1024) fp32
// ---------------------------------------------------------------------------
__global__ __launch_bounds__(256) void pe_kernel(float* __restrict__ pe) {
    int idx = blockIdx.x * 256 + threadIdx.x;         // 50*512
    if (idx >= 50 * 512) return;
    int s = idx >> 9, i = idx & 511;
    float dv = expf((float)(2 * i) * (-9.210340371976184f / 1024.0f));
    float a = (float)s * dv;
    pe[(s << 10) + 2 * i] = sinf(a);
    pe[(s << 10) + 2 * i + 1] = cosf(a);
}

// ---------------------------------------------------------------------------
// NT bf16 GEMM: C(M,N) = A(M,K) * Bt(N,K)^T   — 128x128 tile, BK=64,
// 256 thr (4 waves 2x2, each 64x64), mfma_f32_16x16x32_bf16,
// global_load_lds w/ pre-swizzled source + XOR-swizzled ds_read (T2),
// XCD-chunked bijective block swizzle (T1/m204).
// FLAGS: 1=bias 2=residual(fp32) 4=relu 8=+pe 16=post scale(g,b) 32=out bf16
// ---------------------------------------------------------------------------
template<int FLAGS>
__global__ __launch_bounds__(256) void gemm_bt(
                        const __hip_bfloat16* __restrict__ A,
                        const __hip_bfloat16* __restrict__ Bt,
                        float* __restrict__ outF, __hip_bfloat16* __restrict__ outB,
                        const float* __restrict__ bias, const float* __restrict__ res,
                        const float* __restrict__ pe,
                        const float* __restrict__ psg, const float* __restrict__ psb,
                        int M, int N, int K) {
    __shared__ short lds[16384];                       // A: [0,8192) B: [8192,16384) elems
    const int tid = threadIdx.x;
    const int w = tid >> 6, l = tid & 63;

    // ---- T1: XCD-chunked bijective remap of the linear workgroup id ----
    // HW assigns wg -> XCD (wg % 8); remap so XCD k owns a contiguous chunk
    // of row-stripes (linear id is y-major) -> A-panel reuse within one L2.
    int bx, by;
    {
        const int nwg = gridDim.x * gridDim.y;
        const int wg  = blockIdx.y * gridDim.x + blockIdx.x;
        const int q = nwg >> 3, r = nwg & 7;
        const int xcd = wg & 7, pos = wg >> 3;
        const int nid = (xcd < r) ? xcd * (q + 1) + pos
                                  : r * (q + 1) + (xcd - r) * q + pos;
        by = nid / gridDim.x;
        bx = nid - by * gridDim.x;
    }
    const int row0 = by * 128, col0 = bx * 128;
    const int l15 = l & 15, kof = (l >> 4) << 3;       // frag k-offset (elems)
    const int wr = (w >> 1) << 6, wc = (w & 1) << 6;

    f32x4 acc[4][4];
#pragma unroll
    for (int m = 0; m < 4; ++m)
#pragma unroll
        for (int n = 0; n < 4; ++n) acc[m][n] = (f32x4){0.f, 0.f, 0.f, 0.f};

    // staging geometry: linear LDS slot -> swizzled global column
    int sr[4], sc[4];
#pragma unroll
    for (int c = 0; c < 4; ++c) {
        int e = c * 2048 + w * 512 + l * 8;            // element index in tile
        int r = e >> 6;
        int cb = (e & 63) << 1;                        // byte col (mult of 16)
        sr[c] = r;
        sc[c] = (cb ^ ((r & 7) << 4)) >> 1;            // element col after swizzle
    }
    const int swz = (l15 & 7) << 4;                    // read-side byte XOR

    for (int k0 = 0; k0 < K; k0 += 64) {
#pragma unroll
        for (int c = 0; c < 4; ++c)
            gl2lds16(A + (size_t)(row0 + sr[c]) * K + (k0 + sc[c]),
                     &lds[c * 2048 + w * 512]);
#pragma unroll
        for (int c = 0; c < 4; ++c)
            gl2lds16(Bt + (size_t)(col0 + sr[c]) * K + (k0 + sc[c]),
                     &lds[8192 + c * 2048 + w * 512]);
        __syncthreads();
#pragma unroll
        for (int kk = 0; kk < 64; kk += 32) {
            bfvec8 af[4], bfr[4];
#pragma unroll
            for (int m = 0; m < 4; ++m) {
                int r = wr + m * 16 + l15;
                af[m] = *(const bfvec8*)((const char*)lds + r * 128 + ((((kk + kof) << 1)) ^ swz));
            }
#pragma unroll
            for (int n = 0; n < 4; ++n) {
                int r = wc + n * 16 + l15;
                bfr[n] = *(const bfvec8*)((const char*)lds + 16384 + r * 128 + ((((kk + kof) << 1)) ^ swz));
            }
#pragma unroll
            for (int m = 0; m < 4; ++m)
#pragma unroll
                for (int n = 0; n < 4; ++n)
                    acc[m][n] = __builtin_amdgcn_mfma_f32_16x16x32_bf16(af[m], bfr[n], acc[m][n], 0, 0, 0);
        }
        __syncthreads();
    }

    // epilogue: C/D map col=lane&15, row=(lane>>4)*4+i  [m89-verified]
    const int rb = row0 + wr + ((l >> 4) << 2);
#pragma unroll
    for (int n = 0; n < 4; ++n) {
        const int cidx = col0 + wc + n * 16 + l15;
        float bv = 0.f, pg = 0.f, pb2 = 0.f;
        if constexpr (FLAGS & 1) bv = bias[cidx];
        if constexpr (FLAGS & 16) {
            pg = 0.99999500003749971f * psg[cidx];      // 1/sqrt(1+1e-5) folded in
            pb2 = psb[cidx];
        }
#pragma unroll
        for (int m = 0; m < 4; ++m) {
#pragma unroll
            for (int i = 0; i < 4; ++i) {
                int r = rb + m * 16 + i;
                float v = acc[m][n][i] + bv;
                if constexpr (FLAGS & 8) v += pe[(r % 50) * N + cidx];
                if constexpr (FLAGS & 4) v = fmaxf(v, 0.f);
                if constexpr (FLAGS & 2) v += res[(size_t)r * N + cidx];
                if constexpr (FLAGS & 16) v = v * pg + pb2;
                if constexpr (FLAGS & 32) ((unsigned short*)outB)[(size_t)r * N + cidx] = f2bf(v);
                else outF[(size_t)r * N + cidx] = v;
            }
        }
    }
}

// ---------------------------------------------------------------------------
// LayerNorm (ddof=1, eps added to std): h fp32 (6400,1024) -> bf16 out
// ---------------------------------------------------------------------------
__device__ __forceinline__ float wave_sum(float v) {
#pragma unroll
    for (int off = 32; off; off >>= 1) v += __shfl_down(v, off);
    return v;
}

__global__ __launch_bounds__(256) void ln_kernel(const float* __restrict__ h,
                                                 const float* __restrict__ g,
                                                 const float* __restrict__ b,
                                                 __hip_bfloat16* __restrict__ out) {
    const int row = blockIdx.x, tid = threadIdx.x;
    const float4 v = reinterpret_cast<const float4*>(h + (size_t)row * 1024)[tid];
    float s = v.x + v.y + v.z + v.w;
    float s2 = v.x * v.x + v.y * v.y + v.z * v.z + v.w * v.w;
    __shared__ float red[8];
    float ws1 = wave_sum(s), ws2 = wave_sum(s2);
    if ((tid & 63) == 0) { red[tid >> 6] = ws1; red[4 + (tid >> 6)] = ws2; }
    __syncthreads();
    float sum = red[0] + red[1] + red[2] + red[3];
    float sum2 = red[4] + red[5] + red[6] + red[7];
    float mean = sum * (1.f / 1024.f);
    float var = fmaxf(0.f, (sum2 - sum * mean) * (1.f / 1023.f));
    float inv = 1.f / (sqrtf(var) + 1e-6f);
    float4 gv = reinterpret_cast<const float4*>(g)[tid];
    float4 bv = reinterpret_cast<const float4*>(b)[tid];
    ushort4 o;
    o.x = f2bf(gv.x * (v.x - mean) * inv + bv.x);
    o.y = f2bf(gv.y * (v.y - mean) * inv + bv.y);
    o.z = f2bf(gv.z * (v.z - mean) * inv + bv.z);
    o.w = f2bf(gv.w * (v.w - mean) * inv + bv.w);
    reinterpret_cast<ushort4*>(out)[(size_t)row * 256 + tid] = o;
}

// ---------------------------------------------------------------------------
// Attention: one block per (b,head). qkv bf16 (6400,3072), S=50, dk=64.
// ---------------------------------------------------------------------------
__global__ __launch_bounds__(256) void attn_k(const __hip_bfloat16* __restrict__ qkv,
                                              __hip_bfloat16* __restrict__ o) {
    __shared__ float Q[50][66];
    __shared__ float Kk[50][66];
    __shared__ float V[50][66];
    __shared__ float P[50][52];
    const int bid = blockIdx.x;
    const int b = bid >> 4, hh = bid & 15;
    const int tid = threadIdx.x;
    const size_t base0 = (size_t)(b * 50) * 3072 + hh * 64;
    for (int idx = tid; idx < 3200; idx += 256) {
        int s = idx >> 6, d = idx & 63;
        size_t p = base0 + (size_t)s * 3072 + d;
        Q[s][d] = __bfloat162float(qkv[p]);
        Kk[s][d] = __bfloat162float(qkv[p + 1024]);
        V[s][d] = __bfloat162float(qkv[p + 2048]);
    }
    __syncthreads();
    for (int e = tid; e < 2500; e += 256) {
        int i = e / 50, j = e - i * 50;
        float acc = 0.f;
#pragma unroll
        for (int d = 0; d < 64; ++d) acc += Q[i][d] * Kk[j][d];
        P[i][j] = acc * 0.125f;                        // 1/sqrt(64)
    }
    __syncthreads();
    if (tid < 50) {
        float mx = -1e30f;
        for (int j = 0; j < 50; ++j) mx = fmaxf(mx, P[tid][j]);
        float sum = 0.f;
        for (int j = 0; j < 50; ++j) { float ev = __expf(P[tid][j] - mx); P[tid][j] = ev; sum += ev; }
        float is = 1.f / sum;
        for (int j = 0; j < 50; ++j) P[tid][j] *= is;
    }
    __syncthreads();
    for (int e = tid; e < 3200; e += 256) {
        int i = e >> 6, d = e & 63;
        float acc = 0.f;
#pragma unroll
        for (int j = 0; j < 50; ++j) acc += P[i][j] * V[j][d];
        o[(size_t)(b * 50 + i) * 1024 + hh * 64 + d] = __float2bfloat16(acc);
    }
}

// ---------------------------------------------------------------------------
// Pool: final LN on the 128 last-token rows + cf_bn scale -> bf16 z (128,1024)
// ---------------------------------------------------------------------------
__global__ __launch_bounds__(256) void pool_kernel(const float* __restrict__ h,
                                                   const float* __restrict__ fg,
                                                   const float* __restrict__ fb,
                                                   const float* __restrict__ cg,
                                                   const float* __restrict__ cb,
                                                   __hip_bfloat16* __restrict__ z) {
    const int bb = blockIdx.x, tid = threadIdx.x;
    const size_t row = (size_t)bb * 50 + 49;
    const float4 v = reinterpret_cast<const float4*>(h + row * 1024)[tid];
    float s = v.x + v.y + v.z + v.w;
    float s2 = v.x * v.x + v.y * v.y + v.z * v.z + v.w * v.w;
    __shared__ float red[8];
    float ws1 = wave_sum(s), ws2 = wave_sum(s2);
    if ((tid & 63) == 0) { red[tid >> 6] = ws1; red[4 + (tid >> 6)] = ws2; }
    __syncthreads();
    float sum = red[0] + red[1] + red[2] + red[3];
    float sum2 = red[4] + red[5] + red[6] + red[7];
    float mean = sum * (1.f / 1024.f);
    float var = fmaxf(0.f, (sum2 - sum * mean) * (1.f / 1023.f));
    float inv = 1.f / (sqrtf(var) + 1e-6f);
    const float INV = 0.99999500003749971f;            // 1/sqrt(1+1e-5)
    float4 gv = reinterpret_cast<const float4*>(fg)[tid];
    float4 bv = reinterpret_cast<const float4*>(fb)[tid];
    float4 cgv = reinterpret_cast<const float4*>(cg)[tid];
    float4 cbv = reinterpret_cast<const float4*>(cb)[tid];
    ushort4 o;
    o.x = f2bf((gv.x * (v.x - mean) * inv + bv.x) * INV * cgv.x + cbv.x);
    o.y = f2bf((gv.y * (v.y - mean) * inv + bv.y) * INV * cgv.y + cbv.y);
    o.z = f2bf((gv.z * (v.z - mean) * inv + bv.z) * INV * cgv.z + cbv.z);
    o.w = f2bf((gv.w * (v.w - mean) * inv + bv.w) * INV * cgv.w + cbv.w);
    reinterpret_cast<ushort4*>(z)[(size_t)bb * 256 + tid] = o;
}

// ---------------------------------------------------------------------------
// Final fc: out(128,71) = z3(128,1024) @ fc_w(1024,71) + fc_b
// ---------------------------------------------------------------------------
__global__ __launch_bounds__(128) void fc_kernel(const __hip_bfloat16* __restrict__ z3,
                                                 const float* __restrict__ fw,
                                                 const float* __restrict__ fbias,
                                                 float* __restrict__ out) {
    __shared__ float zr[1024];
    const int b = blockIdx.x, tid = threadIdx.x;
    for (int i = tid; i < 1024; i += 128) zr[i] = __bfloat162float(z3[(size_t)b * 1024 + i]);
    __syncthreads();
    if (tid < 71) {
        float acc = 0.f;
        for (int k = 0; k < 1024; ++k) acc += zr[k] * fw[k * 71 + tid];
        out[b * 71 + tid] = acc + fbias[tid];
    }
}

// ---------------------------------------------------------------------------
extern "C" void kernel_launch(void* const* d_in, const int* in_sizes, int n_in,
                              void* d_out, int out_size, void* d_ws, size_t ws_size,
                              hipStream_t stream) {
    const float* x       = (const float*)d_in[0];
    const float* embed_w = (const float*)d_in[1];
    const float* attn_w  = (const float*)d_in[2];
    const float* attn_b  = (const float*)d_in[3];
    const float* ff_w1   = (const float*)d_in[4];
    const float* ff_b1   = (const float*)d_in[5];
    const float* ff_w2   = (const float*)d_in[6];
    const float* ff_b2   = (const float*)d_in[7];
    const float* ln_g    = (const float*)d_in[8];
    const float* ln_b    = (const float*)d_in[9];
    const float* fin_g   = (const float*)d_in[10];
    const float* fin_b   = (const float*)d_in[11];
    const float* cf_bn_g = (const float*)d_in[12];
    const float* cf_bn_b = (const float*)d_in[13];
    const float* cf_w    = (const float*)d_in[14];
    const float* cf_b    = (const float*)d_in[15];
    const float* fc_bn_g = (const float*)d_in[16];
    const float* fc_bn_b = (const float*)d_in[17];
    const float* fc_w    = (const float*)d_in[18];
    const float* fc_b    = (const float*)d_in[19];

    char* ws = (char*)d_ws;
    size_t off = 0;
    auto alloc = [&](size_t bytes) { void* p = ws + off; off += (bytes + 255) & ~(size_t)255; return p; };

    // weight staging buffer, reused per layer: qkvT(3072x1024) projT(1024x1024)
    // ff1T(4096x1024) ff2T(1024x4096) = 12.58M elems bf16
    __hip_bfloat16* wbuf = (__hip_bfloat16*)alloc((size_t)12582912 * 2);
    float*          h    = (float*)alloc((size_t)MTOT * DMODEL * 4);
    __hip_bfloat16* abuf = (__hip_bfloat16*)alloc((size_t)MTOT * DMODEL * 2);
    __hip_bfloat16* big  = (__hip_bfloat16*)alloc((size_t)MTOT * 4096 * 2);  // xbf | qkv | ffact
    float*          pe   = (float*)alloc((size_t)50 * 1024 * 4);
    __hip_bfloat16* zbuf = (__hip_bfloat16*)alloc((size_t)128 * 1024 * 2);
    __hip_bfloat16* z3   = (__hip_bfloat16*)alloc((size_t)128 * 1024 * 2);

    __hip_bfloat16* qkvT = wbuf;
    __hip_bfloat16* projT = wbuf + (size_t)3072 * 1024;
    __hip_bfloat16* ff1T = wbuf + (size_t)4096 * 1024;
    __hip_bfloat16* ff2T = wbuf + (size_t)8192 * 1024;

    const dim3 tb(32, 8);

    // ---- prologue: x conversion, PE table, embedding GEMM (+PE) ----
    xconv<<<(MTOT * (KEMB / 4) + 255) / 256, 256, 0, stream>>>(x, big);
    pe_kernel<<<100, 256, 0, stream>>>(pe);
    tconv<<<dim3(32, 38), tb, 0, stream>>>(embed_w, wbuf, 1200, 1024, KEMB);
    gemm_bt<8><<<dim3(8, 50), 256, 0, stream>>>(big, wbuf, h, nullptr,
        nullptr, nullptr, pe, nullptr, nullptr, MTOT, DMODEL, KEMB);

    // ---- 5 transformer layers ----
    for (int i = 0; i < 5; ++i) {
        for (int k = 0; k < 3; ++k)
            tconv<<<dim3(32, 32), tb, 0, stream>>>(attn_w + ((size_t)i * 4 + k) * 1048576,
                                                   qkvT + (size_t)k * 1048576, 1024, 1024, 1024);
        tconv<<<dim3(32, 32), tb, 0, stream>>>(attn_w + ((size_t)i * 4 + 3) * 1048576,
                                               projT, 1024, 1024, 1024);
        tconv<<<dim3(128, 32), tb, 0, stream>>>(ff_w1 + (size_t)i * 4194304, ff1T, 1024, 4096, 1024);
        tconv<<<dim3(32, 128), tb, 0, stream>>>(ff_w2 + (size_t)i * 4194304, ff2T, 4096, 1024, 4096);

        // ln1 -> a
        ln_kernel<<<MTOT, 256, 0, stream>>>(h, ln_g + (size_t)i * 2048, ln_b + (size_t)i * 2048, abuf);
        // qkv = a @ Wqkv + b   (bf16 out)
        gemm_bt<33><<<dim3(24, 50), 256, 0, stream>>>(abuf, qkvT, nullptr, big,
            attn_b + (size_t)i * 4096, nullptr, nullptr, nullptr, nullptr, MTOT, 3072, 1024);
        // attention -> o (reuse abuf)
        attn_k<<<2048, 256, 0, stream>>>(big, abuf);
        // h += o @ Wo + bo
        gemm_bt<3><<<dim3(8, 50), 256, 0, stream>>>(abuf, projT, h, nullptr,
            attn_b + (size_t)i * 4096 + 3072, h, nullptr, nullptr, nullptr, MTOT, DMODEL, 1024);
        // ln2 -> a2
        ln_kernel<<<MTOT, 256, 0, stream>>>(h, ln_g + (size_t)i * 2048 + 1024,
                                            ln_b + (size_t)i * 2048 + 1024, abuf);
        // ffact = relu(a2 @ W1 + b1)  (bf16)
        gemm_bt<37><<<dim3(32, 50), 256, 0, stream>>>(abuf, ff1T, nullptr, big,
            ff_b1 + (size_t)i * 4096, nullptr, nullptr, nullptr, nullptr, MTOT, 4096, 1024);
        // h += ffact @ W2 + b2
        gemm_bt<3><<<dim3(8, 50), 256, 0, stream>>>(big, ff2T, h, nullptr,
            ff_b2 + (size_t)i * 1024, h, nullptr, nullptr, nullptr, MTOT, DMODEL, 4096);
    }

    // ---- head ----
    pool_kernel<<<128, 256, 0, stream>>>(h, fin_g, fin_b, cf_bn_g, cf_bn_b, zbuf);
    tconv<<<dim3(32, 32), tb, 0, stream>>>(cf_w, wbuf, 1024, 1024, 1024);
    gemm_bt<53><<<dim3(8, 1), 256, 0, stream>>>(zbuf, wbuf, nullptr, z3,
        cf_b, nullptr, nullptr, fc_bn_g, fc_bn_b, 128, 1024, 1024);
    fc_kernel<<<128, 128, 0, stream>>>(z3, fc_w, fc_b, (float*)d_out);

    (void)in_sizes; (void)n_in; (void)out_size; (void)ws_size;
}

// Round 5
// 1894.652 us; speedup vs baseline: 1.1441x; 1.1441x over previous
//
#include <hip/hip_runtime.h>
#include <hip/hip_bf16.h>

// ---------------------------------------------------------------------------
// MF_Transformer: B=128, SL=5000, CH=12, HZ=100 -> tokens M=6400, S=50, D=1024
// L=5, DFF=4096, H=16, dk=64, NC=71. All heavy GEMMs in bf16 MFMA (fp32 acc).
// R3/R4: T1 XCD-chunked swizzle (FETCH halved; GEMMs latency-bound, not BW).
// R5: MFMA attention (1 wave/head) replacing VALU attn; batched attn tconv.
// ---------------------------------------------------------------------------

typedef __attribute__((ext_vector_type(4))) float f32x4;
typedef __attribute__((ext_vector_type(8))) __bf16 bfvec8;

#define MTOT 6400      // B*S
#define DMODEL 1024
#define KEMB 1216      // 1200 padded to multiple of 64

__device__ __forceinline__ unsigned short f2bf(float x) {
    __hip_bfloat16 t = __float2bfloat16(x);
    return *reinterpret_cast<unsigned short*>(&t);
}

__device__ __forceinline__ void gl2lds16(const void* g, void* l) {
    __builtin_amdgcn_global_load_lds(
        (__attribute__((address_space(1))) void*)(g),
        (__attribute__((address_space(3))) void*)(l), 16, 0, 0);
}

// ---------------------------------------------------------------------------
// Transpose-convert: W fp32 (K,N) -> Wt bf16 (N,Kpad), zero-pad k in [K,Kpad)
// blockIdx.z picks matrix z at offset z*zoff in both src and dst.
// ---------------------------------------------------------------------------
__global__ __launch_bounds__(256) void tconv(const float* __restrict__ W,
                                             __hip_bfloat16* __restrict__ Wt,
                                             int K, int N, int Kpad, size_t zoff) {
    __shared__ float t[32][33];
    const float* Wz = W + (size_t)blockIdx.z * zoff;
    unsigned short* Wtz = (unsigned short*)Wt + (size_t)blockIdx.z * zoff;
    const int n0 = blockIdx.x * 32, k0 = blockIdx.y * 32;
    const int tx = threadIdx.x, ty = threadIdx.y;   // block (32,8)
#pragma unroll
    for (int j = 0; j < 4; ++j) {
        int k = k0 + ty + j * 8, n = n0 + tx;
        float v = (k < K && n < N) ? Wz[(size_t)k * N + n] : 0.f;
        t[ty + j * 8][tx] = v;
    }
    __syncthreads();
#pragma unroll
    for (int j = 0; j < 4; ++j) {
        int n = n0 + ty + j * 8, k = k0 + tx;
        if (n < N && k < Kpad)
            Wtz[(size_t)n * Kpad + k] = f2bf(t[tx][ty + j * 8]);
    }
}

// ---------------------------------------------------------------------------
// x fp32 (6400,1200) -> bf16 (6400,1216) zero-padded
// ---------------------------------------------------------------------------
__global__ __launch_bounds__(256) void xconv(const float* __restrict__ x,
                                             __hip_bfloat16* __restrict__ xb) {
    int q = blockIdx.x * 256 + threadIdx.x;           // quads: 6400*304
    if (q >= MTOT * (KEMB / 4)) return;
    int m = q / (KEMB / 4), kq = q - m * (KEMB / 4);
    ushort4 o;
    if (kq < 300) {
        float4 v = reinterpret_cast<const float4*>(x + (size_t)m * 1200)[kq];
        o.x = f2bf(v.x); o.y = f2bf(v.y); o.z = f2bf(v.z); o.w = f2bf(v.w);
    } else { o.x = 0; o.y = 0; o.z = 0; o.w = 0; }
    reinterpret_cast<ushort4*>(xb)[q] = o;
}

// ---------------------------------------------------------------------------
// positional encoding table (50,1024) fp32
// ---------------------------------------------------------------------------
__global__ __launch_bounds__(256) void pe_kernel(float* __restrict__ pe) {
    int idx = blockIdx.x * 256 + threadIdx.x;         // 50*512
    if (idx >= 50 * 512) return;
    int s = idx >> 9, i = idx & 511;
    float dv = expf((float)(2 * i) * (-9.210340371976184f / 1024.0f));
    float a = (float)s * dv;
    pe[(s << 10) + 2 * i] = sinf(a);
    pe[(s << 10) + 2 * i + 1] = cosf(a);
}

// ---------------------------------------------------------------------------
// NT bf16 GEMM: C(M,N) = A(M,K) * Bt(N,K)^T   — 128x128 tile, BK=64,
// 256 thr (4 waves 2x2, each 64x64), mfma_f32_16x16x32_bf16,
// global_load_lds w/ pre-swizzled source + XOR-swizzled ds_read (T2),
// XCD-chunked bijective block swizzle (T1/m204).
// FLAGS: 1=bias 2=residual(fp32) 4=relu 8=+pe 16=post scale(g,b) 32=out bf16
// ---------------------------------------------------------------------------
template<int FLAGS>
__global__ __launch_bounds__(256) void gemm_bt(
                        const __hip_bfloat16* __restrict__ A,
                        const __hip_bfloat16* __restrict__ Bt,
                        float* __restrict__ outF, __hip_bfloat16* __restrict__ outB,
                        const float* __restrict__ bias, const float* __restrict__ res,
                        const float* __restrict__ pe,
                        const float* __restrict__ psg, const float* __restrict__ psb,
                        int M, int N, int K) {
    __shared__ short lds[16384];                       // A: [0,8192) B: [8192,16384) elems
    const int tid = threadIdx.x;
    const int w = tid >> 6, l = tid & 63;

    // ---- T1: XCD-chunked bijective remap of the linear workgroup id ----
    int bx, by;
    {
        const int nwg = gridDim.x * gridDim.y;
        const int wg  = blockIdx.y * gridDim.x + blockIdx.x;
        const int q = nwg >> 3, r = nwg & 7;
        const int xcd = wg & 7, pos = wg >> 3;
        const int nid = (xcd < r) ? xcd * (q + 1) + pos
                                  : r * (q + 1) + (xcd - r) * q + pos;
        by = nid / gridDim.x;
        bx = nid - by * gridDim.x;
    }
    const int row0 = by * 128, col0 = bx * 128;
    const int l15 = l & 15, kof = (l >> 4) << 3;       // frag k-offset (elems)
    const int wr = (w >> 1) << 6, wc = (w & 1) << 6;

    f32x4 acc[4][4];
#pragma unroll
    for (int m = 0; m < 4; ++m)
#pragma unroll
        for (int n = 0; n < 4; ++n) acc[m][n] = (f32x4){0.f, 0.f, 0.f, 0.f};

    // staging geometry: linear LDS slot -> swizzled global column
    int sr[4], sc[4];
#pragma unroll
    for (int c = 0; c < 4; ++c) {
        int e = c * 2048 + w * 512 + l * 8;            // element index in tile
        int r = e >> 6;
        int cb = (e & 63) << 1;                        // byte col (mult of 16)
        sr[c] = r;
        sc[c] = (cb ^ ((r & 7) << 4)) >> 1;            // element col after swizzle
    }
    const int swz = (l15 & 7) << 4;                    // read-side byte XOR

    for (int k0 = 0; k0 < K; k0 += 64) {
#pragma unroll
        for (int c = 0; c < 4; ++c)
            gl2lds16(A + (size_t)(row0 + sr[c]) * K + (k0 + sc[c]),
                     &lds[c * 2048 + w * 512]);
#pragma unroll
        for (int c = 0; c < 4; ++c)
            gl2lds16(Bt + (size_t)(col0 + sr[c]) * K + (k0 + sc[c]),
                     &lds[8192 + c * 2048 + w * 512]);
        __syncthreads();
#pragma unroll
        for (int kk = 0; kk < 64; kk += 32) {
            bfvec8 af[4], bfr[4];
#pragma unroll
            for (int m = 0; m < 4; ++m) {
                int r = wr + m * 16 + l15;
                af[m] = *(const bfvec8*)((const char*)lds + r * 128 + ((((kk + kof) << 1)) ^ swz));
            }
#pragma unroll
            for (int n = 0; n < 4; ++n) {
                int r = wc + n * 16 + l15;
                bfr[n] = *(const bfvec8*)((const char*)lds + 16384 + r * 128 + ((((kk + kof) << 1)) ^ swz));
            }
#pragma unroll
            for (int m = 0; m < 4; ++m)
#pragma unroll
                for (int n = 0; n < 4; ++n)
                    acc[m][n] = __builtin_amdgcn_mfma_f32_16x16x32_bf16(af[m], bfr[n], acc[m][n], 0, 0, 0);
        }
        __syncthreads();
    }

    // epilogue: C/D map col=lane&15, row=(lane>>4)*4+i  [m89-verified]
    const int rb = row0 + wr + ((l >> 4) << 2);
#pragma unroll
    for (int n = 0; n < 4; ++n) {
        const int cidx = col0 + wc + n * 16 + l15;
        float bv = 0.f, pg = 0.f, pb2 = 0.f;
        if constexpr (FLAGS & 1) bv = bias[cidx];
        if constexpr (FLAGS & 16) {
            pg = 0.99999500003749971f * psg[cidx];      // 1/sqrt(1+1e-5) folded in
            pb2 = psb[cidx];
        }
#pragma unroll
        for (int m = 0; m < 4; ++m) {
#pragma unroll
            for (int i = 0; i < 4; ++i) {
                int r = rb + m * 16 + i;
                float v = acc[m][n][i] + bv;
                if constexpr (FLAGS & 8) v += pe[(r % 50) * N + cidx];
                if constexpr (FLAGS & 4) v = fmaxf(v, 0.f);
                if constexpr (FLAGS & 2) v += res[(size_t)r * N + cidx];
                if constexpr (FLAGS & 16) v = v * pg + pb2;
                if constexpr (FLAGS & 32) ((unsigned short*)outB)[(size_t)r * N + cidx] = f2bf(v);
                else outF[(size_t)r * N + cidx] = v;
            }
        }
    }
}

// ---------------------------------------------------------------------------
// LayerNorm (ddof=1, eps added to std): h fp32 (6400,1024) -> bf16 out
// ---------------------------------------------------------------------------
__device__ __forceinline__ float wave_sum(float v) {
#pragma unroll
    for (int off = 32; off; off >>= 1) v += __shfl_down(v, off);
    return v;
}

__global__ __launch_bounds__(256) void ln_kernel(const float* __restrict__ h,
                                                 const float* __restrict__ g,
                                                 const float* __restrict__ b,
                                                 __hip_bfloat16* __restrict__ out) {
    const int row = blockIdx.x, tid = threadIdx.x;
    const float4 v = reinterpret_cast<const float4*>(h + (size_t)row * 1024)[tid];
    float s = v.x + v.y + v.z + v.w;
    float s2 = v.x * v.x + v.y * v.y + v.z * v.z + v.w * v.w;
    __shared__ float red[8];
    float ws1 = wave_sum(s), ws2 = wave_sum(s2);
    if ((tid & 63) == 0) { red[tid >> 6] = ws1; red[4 + (tid >> 6)] = ws2; }
    __syncthreads();
    float sum = red[0] + red[1] + red[2] + red[3];
    float sum2 = red[4] + red[5] + red[6] + red[7];
    float mean = sum * (1.f / 1024.f);
    float var = fmaxf(0.f, (sum2 - sum * mean) * (1.f / 1023.f));
    float inv = 1.f / (sqrtf(var) + 1e-6f);
    float4 gv = reinterpret_cast<const float4*>(g)[tid];
    float4 bv = reinterpret_cast<const float4*>(b)[tid];
    ushort4 o;
    o.x = f2bf(gv.x * (v.x - mean) * inv + bv.x);
    o.y = f2bf(gv.y * (v.y - mean) * inv + bv.y);
    o.z = f2bf(gv.z * (v.z - mean) * inv + bv.z);
    o.w = f2bf(gv.w * (v.w - mean) * inv + bv.w);
    reinterpret_cast<ushort4*>(out)[(size_t)row * 256 + tid] = o;
}

// ---------------------------------------------------------------------------
// MFMA attention: 1 wave per (b,head); 2 heads per block (128 thr).
// qkv bf16 (6400,3072) rows token-major [Q|K|V], head-major cols (16x64).
// S = QK^T (64x64 padded), wave-parallel softmax, O = P V via 2nd MFMA pass.
// P and V^T staged per-wave in LDS with stride-72 rows (bank-friendly).
// ---------------------------------------------------------------------------
__global__ __launch_bounds__(128) void attn_mfma(const __hip_bfloat16* __restrict__ qkv,
                                                 __hip_bfloat16* __restrict__ o) {
    __shared__ unsigned short plds[2][64 * 72];
    __shared__ unsigned short vlds[2][64 * 72];
    const int w = threadIdx.x >> 6, l = threadIdx.x & 63;
    const int b = blockIdx.x >> 3;                       // 0..127
    const int hh = ((blockIdx.x & 7) << 1) | w;          // 0..15
    const int l15 = l & 15, g = l >> 4;
    const size_t rowbase = (size_t)(b * 50) * 3072 + hh * 64;

    // ---- stage V^T into LDS (issue early; hides under QK^T) ----
    {
        const int j = l;
        const bool ok = j < 50;
        const uint4* vp = (const uint4*)(qkv + rowbase + (size_t)j * 3072 + 2048);
#pragma unroll
        for (int d8 = 0; d8 < 8; ++d8) {
            uint4 vv = ok ? vp[d8] : (uint4){0u, 0u, 0u, 0u};
            const int d0 = d8 * 8;
            vlds[w][(d0 + 0) * 72 + j] = (unsigned short)(vv.x & 0xffff);
            vlds[w][(d0 + 1) * 72 + j] = (unsigned short)(vv.x >> 16);
            vlds[w][(d0 + 2) * 72 + j] = (unsigned short)(vv.y & 0xffff);
            vlds[w][(d0 + 3) * 72 + j] = (unsigned short)(vv.y >> 16);
            vlds[w][(d0 + 4) * 72 + j] = (unsigned short)(vv.z & 0xffff);
            vlds[w][(d0 + 5) * 72 + j] = (unsigned short)(vv.z >> 16);
            vlds[w][(d0 + 6) * 72 + j] = (unsigned short)(vv.w & 0xffff);
            vlds[w][(d0 + 7) * 72 + j] = (unsigned short)(vv.w >> 16);
        }
    }

    // ---- load Q,K fragments (NT layout: lane row=l15, k-offset g*8) ----
    const bfvec8 zf = {};
    bfvec8 qf[4][2], kf[4][2];
#pragma unroll
    for (int mi = 0; mi < 4; ++mi) {
        const int i = mi * 16 + l15;
        const bool ok = i < 50;
        const size_t rq = rowbase + (size_t)i * 3072;
#pragma unroll
        for (int ks = 0; ks < 2; ++ks) {
            const int d = ks * 32 + g * 8;
            qf[mi][ks] = ok ? *(const bfvec8*)(qkv + rq + d) : zf;
            kf[mi][ks] = ok ? *(const bfvec8*)(qkv + rq + 1024 + d) : zf;
        }
    }

    // ---- S = Q K^T ----
    f32x4 s[4][4];
#pragma unroll
    for (int mi = 0; mi < 4; ++mi)
#pragma unroll
        for (int nj = 0; nj < 4; ++nj) {
            s[mi][nj] = (f32x4){0.f, 0.f, 0.f, 0.f};
#pragma unroll
            for (int ks = 0; ks < 2; ++ks)
                s[mi][nj] = __builtin_amdgcn_mfma_f32_16x16x32_bf16(qf[mi][ks], kf[nj][ks], s[mi][nj], 0, 0, 0);
        }

    // ---- wave-parallel softmax (rows live in 16-lane groups) ----
#pragma unroll
    for (int mi = 0; mi < 4; ++mi) {
#pragma unroll
        for (int r = 0; r < 4; ++r) {
            const int row = mi * 16 + g * 4 + r;
            float v[4];
            float mx = -1e30f;
#pragma unroll
            for (int nj = 0; nj < 4; ++nj) {
                float x = s[mi][nj][r] * 0.125f;        // 1/sqrt(64)
                if (nj * 16 + l15 >= 50) x = -1e30f;    // mask padded keys
                v[nj] = x;
                mx = fmaxf(mx, x);
            }
#pragma unroll
            for (int m = 1; m < 16; m <<= 1) mx = fmaxf(mx, __shfl_xor(mx, m));
            float sum = 0.f;
#pragma unroll
            for (int nj = 0; nj < 4; ++nj) { v[nj] = __expf(v[nj] - mx); sum += v[nj]; }
#pragma unroll
            for (int m = 1; m < 16; m <<= 1) sum += __shfl_xor(sum, m);
            const float is = 1.f / sum;
#pragma unroll
            for (int nj = 0; nj < 4; ++nj)
                plds[w][row * 72 + nj * 16 + l15] = f2bf(v[nj] * is);
        }
    }
    __syncthreads();

    // ---- O = P V ----
    bfvec8 pa[4][2], vb[4][2];
#pragma unroll
    for (int mi = 0; mi < 4; ++mi)
#pragma unroll
        for (int ks = 0; ks < 2; ++ks)
            pa[mi][ks] = *(const bfvec8*)(plds[w] + (mi * 16 + l15) * 72 + ks * 32 + g * 8);
#pragma unroll
    for (int dn = 0; dn < 4; ++dn)
#pragma unroll
        for (int ks = 0; ks < 2; ++ks)
            vb[dn][ks] = *(const bfvec8*)(vlds[w] + (dn * 16 + l15) * 72 + ks * 32 + g * 8);

    f32x4 oa[4][4];
#pragma unroll
    for (int mi = 0; mi < 4; ++mi)
#pragma unroll
        for (int dn = 0; dn < 4; ++dn) {
            oa[mi][dn] = (f32x4){0.f, 0.f, 0.f, 0.f};
#pragma unroll
            for (int ks = 0; ks < 2; ++ks)
                oa[mi][dn] = __builtin_amdgcn_mfma_f32_16x16x32_bf16(pa[mi][ks], vb[dn][ks], oa[mi][dn], 0, 0, 0);
        }

    // ---- store O (col=l15, row=g*4+r per tile) ----
#pragma unroll
    for (int mi = 0; mi < 4; ++mi) {
#pragma unroll
        for (int r = 0; r < 4; ++r) {
            const int i = mi * 16 + g * 4 + r;
            if (i < 50) {
                const size_t ob = (size_t)(b * 50 + i) * 1024 + hh * 64;
#pragma unroll
                for (int dn = 0; dn < 4; ++dn)
                    ((unsigned short*)o)[ob + dn * 16 + l15] = f2bf(oa[mi][dn][r]);
            }
        }
    }
}

// ---------------------------------------------------------------------------
// Pool: final LN on the 128 last-token rows + cf_bn scale -> bf16 z (128,1024)
// ---------------------------------------------------------------------------
__global__ __launch_bounds__(256) void pool_kernel(const float* __restrict__ h,
                                                   const float* __restrict__ fg,
                                                   const float* __restrict__ fb,
                                                   const float* __restrict__ cg,
                                                   const float* __restrict__ cb,
                                                   __hip_bfloat16* __restrict__ z) {
    const int bb = blockIdx.x, tid = threadIdx.x;
    const size_t row = (size_t)bb * 50 + 49;
    const float4 v = reinterpret_cast<const float4*>(h + row * 1024)[tid];
    float s = v.x + v.y + v.z + v.w;
    float s2 = v.x * v.x + v.y * v.y + v.z * v.z + v.w * v.w;
    __shared__ float red[8];
    float ws1 = wave_sum(s), ws2 = wave_sum(s2);
    if ((tid & 63) == 0) { red[tid >> 6] = ws1; red[4 + (tid >> 6)] = ws2; }
    __syncthreads();
    float sum = red[0] + red[1] + red[2] + red[3];
    float sum2 = red[4] + red[5] + red[6] + red[7];
    float mean = sum * (1.f / 1024.f);
    float var = fmaxf(0.f, (sum2 - sum * mean) * (1.f / 1023.f));
    float inv = 1.f / (sqrtf(var) + 1e-6f);
    const float INV = 0.99999500003749971f;            // 1/sqrt(1+1e-5)
    float4 gv = reinterpret_cast<const float4*>(fg)[tid];
    float4 bv = reinterpret_cast<const float4*>(fb)[tid];
    float4 cgv = reinterpret_cast<const float4*>(cg)[tid];
    float4 cbv = reinterpret_cast<const float4*>(cb)[tid];
    ushort4 o;
    o.x = f2bf((gv.x * (v.x - mean) * inv + bv.x) * INV * cgv.x + cbv.x);
    o.y = f2bf((gv.y * (v.y - mean) * inv + bv.y) * INV * cgv.y + cbv.y);
    o.z = f2bf((gv.z * (v.z - mean) * inv + bv.z) * INV * cgv.z + cbv.z);
    o.w = f2bf((gv.w * (v.w - mean) * inv + bv.w) * INV * cgv.w + cbv.w);
    reinterpret_cast<ushort4*>(z)[(size_t)bb * 256 + tid] = o;
}

// ---------------------------------------------------------------------------
// Final fc: out(128,71) = z3(128,1024) @ fc_w(1024,71) + fc_b
// ---------------------------------------------------------------------------
__global__ __launch_bounds__(128) void fc_kernel(const __hip_bfloat16* __restrict__ z3,
                                                 const float* __restrict__ fw,
                                                 const float* __restrict__ fbias,
                                                 float* __restrict__ out) {
    __shared__ float zr[1024];
    const int b = blockIdx.x, tid = threadIdx.x;
    for (int i = tid; i < 1024; i += 128) zr[i] = __bfloat162float(z3[(size_t)b * 1024 + i]);
    __syncthreads();
    if (tid < 71) {
        float acc = 0.f;
        for (int k = 0; k < 1024; ++k) acc += zr[k] * fw[k * 71 + tid];
        out[b * 71 + tid] = acc + fbias[tid];
    }
}

// ---------------------------------------------------------------------------
extern "C" void kernel_launch(void* const* d_in, const int* in_sizes, int n_in,
                              void* d_out, int out_size, void* d_ws, size_t ws_size,
                              hipStream_t stream) {
    const float* x       = (const float*)d_in[0];
    const float* embed_w = (const float*)d_in[1];
    const float* attn_w  = (const float*)d_in[2];
    const float* attn_b  = (const float*)d_in[3];
    const float* ff_w1   = (const float*)d_in[4];
    const float* ff_b1   = (const float*)d_in[5];
    const float* ff_w2   = (const float*)d_in[6];
    const float* ff_b2   = (const float*)d_in[7];
    const float* ln_g    = (const float*)d_in[8];
    const float* ln_b    = (const float*)d_in[9];
    const float* fin_g   = (const float*)d_in[10];
    const float* fin_b   = (const float*)d_in[11];
    const float* cf_bn_g = (const float*)d_in[12];
    const float* cf_bn_b = (const float*)d_in[13];
    const float* cf_w    = (const float*)d_in[14];
    const float* cf_b    = (const float*)d_in[15];
    const float* fc_bn_g = (const float*)d_in[16];
    const float* fc_bn_b = (const float*)d_in[17];
    const float* fc_w    = (const float*)d_in[18];
    const float* fc_b    = (const float*)d_in[19];

    char* ws = (char*)d_ws;
    size_t off = 0;
    auto alloc = [&](size_t bytes) { void* p = ws + off; off += (bytes + 255) & ~(size_t)255; return p; };

    // weight staging buffer, reused per layer: qkvT(3072x1024) projT(1024x1024)
    // ff1T(4096x1024) ff2T(1024x4096) = 12.58M elems bf16
    __hip_bfloat16* wbuf = (__hip_bfloat16*)alloc((size_t)12582912 * 2);
    float*          h    = (float*)alloc((size_t)MTOT * DMODEL * 4);
    __hip_bfloat16* abuf = (__hip_bfloat16*)alloc((size_t)MTOT * DMODEL * 2);
    __hip_bfloat16* big  = (__hip_bfloat16*)alloc((size_t)MTOT * 4096 * 2);  // xbf | qkv | ffact
    float*          pe   = (float*)alloc((size_t)50 * 1024 * 4);
    __hip_bfloat16* zbuf = (__hip_bfloat16*)alloc((size_t)128 * 1024 * 2);
    __hip_bfloat16* z3   = (__hip_bfloat16*)alloc((size_t)128 * 1024 * 2);

    __hip_bfloat16* qkvT = wbuf;                          // 4 attn mats contiguous
    __hip_bfloat16* ff1T = wbuf + (size_t)4096 * 1024;
    __hip_bfloat16* ff2T = wbuf + (size_t)8192 * 1024;
    __hip_bfloat16* projT = wbuf + (size_t)3072 * 1024;

    const dim3 tb(32, 8);

    // ---- prologue: x conversion, PE table, embedding GEMM (+PE) ----
    xconv<<<(MTOT * (KEMB / 4) + 255) / 256, 256, 0, stream>>>(x, big);
    pe_kernel<<<100, 256, 0, stream>>>(pe);
    tconv<<<dim3(32, 38), tb, 0, stream>>>(embed_w, wbuf, 1200, 1024, KEMB, 0);
    gemm_bt<8><<<dim3(8, 50), 256, 0, stream>>>(big, wbuf, h, nullptr,
        nullptr, nullptr, pe, nullptr, nullptr, MTOT, DMODEL, KEMB);

    // ---- 5 transformer layers ----
    for (int i = 0; i < 5; ++i) {
        // all 4 attention weight matrices in one batched launch (z = 0..3)
        tconv<<<dim3(32, 32, 4), tb, 0, stream>>>(attn_w + (size_t)i * 4194304,
                                                  qkvT, 1024, 1024, 1024, 1048576);
        tconv<<<dim3(128, 32), tb, 0, stream>>>(ff_w1 + (size_t)i * 4194304, ff1T, 1024, 4096, 1024, 0);
        tconv<<<dim3(32, 128), tb, 0, stream>>>(ff_w2 + (size_t)i * 4194304, ff2T, 4096, 1024, 4096, 0);

        // ln1 -> a
        ln_kernel<<<MTOT, 256, 0, stream>>>(h, ln_g + (size_t)i * 2048, ln_b + (size_t)i * 2048, abuf);
        // qkv = a @ Wqkv + b   (bf16 out)
        gemm_bt<33><<<dim3(24, 50), 256, 0, stream>>>(abuf, qkvT, nullptr, big,
            attn_b + (size_t)i * 4096, nullptr, nullptr, nullptr, nullptr, MTOT, 3072, 1024);
        // attention -> o (reuse abuf)
        attn_mfma<<<1024, 128, 0, stream>>>(big, abuf);
        // h += o @ Wo + bo
        gemm_bt<3><<<dim3(8, 50), 256, 0, stream>>>(abuf, projT, h, nullptr,
            attn_b + (size_t)i * 4096 + 3072, h, nullptr, nullptr, nullptr, MTOT, DMODEL, 1024);
        // ln2 -> a2
        ln_kernel<<<MTOT, 256, 0, stream>>>(h, ln_g + (size_t)i * 2048 + 1024,
                                            ln_b + (size_t)i * 2048 + 1024, abuf);
        // ffact = relu(a2 @ W1 + b1)  (bf16)
        gemm_bt<37><<<dim3(32, 50), 256, 0, stream>>>(abuf, ff1T, nullptr, big,
            ff_b1 + (size_t)i * 4096, nullptr, nullptr, nullptr, nullptr, MTOT, 4096, 1024);
        // h += ffact @ W2 + b2
        gemm_bt<3><<<dim3(8, 50), 256, 0, stream>>>(big, ff2T, h, nullptr,
            ff_b2 + (size_t)i * 1024, h, nullptr, nullptr, nullptr, MTOT, DMODEL, 4096);
    }

    // ---- head ----
    pool_kernel<<<128, 256, 0, stream>>>(h, fin_g, fin_b, cf_bn_g, cf_bn_b, zbuf);
    tconv<<<dim3(32, 32), tb, 0, stream>>>(cf_w, wbuf, 1024, 1024, 1024, 0);
    gemm_bt<53><<<dim3(8, 1), 256, 0, stream>>>(zbuf, wbuf, nullptr, z3,
        cf_b, nullptr, nullptr, fc_bn_g, fc_bn_b, 128, 1024, 1024);
    fc_kernel<<<128, 128, 0, stream>>>(z3, fc_w, fc_b, (float*)d_out);

    (void)in_sizes; (void)n_in; (void)out_size; (void)ws_size;
}